// Round 1
// baseline (81.574 us; speedup 1.0000x reference)
//
#include <hip/hip_runtime.h>

// Problem constants (match reference setup_inputs / _pool_matrix)
#define DISP_RANGE 10
#define OUT_D 21
#define B_ 8
#define A_ 9
#define D_ 128
#define H_ 64
#define W_ 64
#define HW_ (H_ * W_)   // 4096

// cost[b,0,a,k,h,w] = wt * sum_{dd in [start0+s, start0+e)} uh[b,a, dd-32+h, h, w]   (0 if row OOB)
// cost[b,1,a,k,h,w] = wt * sum_{dd in [start0+s, start0+e)} vw[b,a, dd-32+w, h, w]   (0 if row OOB)
// One block per (b,a,h). uh path reads wave-uniform rows directly (coalesced).
// vw path stages rows [lo,hi) of the [128][64] slice into LDS; diagonal read is
// stride-65 in LDS words -> bank-conflict-free.
__global__ __launch_bounds__(256) void cost_volume_kernel(
    const float* __restrict__ uh,
    const float* __restrict__ vw,
    float* __restrict__ out)
{
    __shared__ float lds[D_ * W_];   // 32 KiB max usage

    const int h = blockIdx.x;
    const int a = blockIdx.y;
    const int b = blockIdx.z;
    const int t = (int)threadIdx.x;
    const int w  = t & 63;           // lane within wave
    const int kg = t >> 6;           // wave id 0..3 -> owns k = kg, kg+4, ...

    const int ad     = max(abs(a - 4), 1);
    const int L      = 2 * DISP_RANGE * ad + 1;      // 21..81
    const int start0 = (D_ / 2) - DISP_RANGE * ad;   // 24..54
    // vw rows actually touched: din = dd-32+w, dd in [start0, start0+L), w in [0,64)
    const int lo = max(0, start0 - 32);
    const int hi = min(D_, start0 + L + 31);

    const size_t slice = (size_t)(b * A_ + a) * D_ * HW_ + (size_t)h * W_;

    // ---- stage vw rows [lo,hi) into LDS, float4-coalesced ----
    {
        const int nrows = hi - lo;
        const int fi = t & 15;       // float4 col within 64-float row
        const int r0 = t >> 4;       // 16 rows staged per iteration
        for (int r = r0; r < nrows; r += 16) {
            const float4 v = *reinterpret_cast<const float4*>(
                vw + slice + (size_t)(lo + r) * HW_ + (size_t)(fi * 4));
            *reinterpret_cast<float4*>(&lds[r * W_ + fi * 4]) = v;
        }
    }
    __syncthreads();

    const size_t out_b = ((size_t)b * 2) * A_ * OUT_D * HW_;
    const size_t out_base0 = out_b + ((size_t)a * OUT_D) * HW_ + (size_t)h * W_ + w;
    const size_t out_base1 = out_base0 + (size_t)A_ * OUT_D * HW_;

    for (int k = kg; k < OUT_D; k += 4) {
        const int s = (k * L) / OUT_D;
        const int e = ((k + 1) * L + OUT_D - 1) / OUT_D;   // ceil
        const float wt = 1.0f / (float)(e - s);

        // n=1 (vw) from LDS: addr = (dd-32-lo)*64 + 65*w -> conflict-free
        float acc1 = 0.0f;
        for (int dd = start0 + s; dd < start0 + e; ++dd) {
            const int din = dd - 32 + w;
            if (din >= lo && din < hi)
                acc1 += lds[(din - lo) * W_ + w];
        }

        // n=0 (uh) direct from global: row uniform across wave -> coalesced
        float acc0 = 0.0f;
        for (int dd = start0 + s; dd < start0 + e; ++dd) {
            const int din = dd - 32 + h;
            if (din >= 0 && din < D_)
                acc0 += uh[slice + (size_t)din * HW_ + (size_t)w];
        }

        out[out_base0 + (size_t)k * HW_] = acc0 * wt;
        out[out_base1 + (size_t)k * HW_] = acc1 * wt;
    }
}

extern "C" void kernel_launch(void* const* d_in, const int* in_sizes, int n_in,
                              void* d_out, int out_size, void* d_ws, size_t ws_size,
                              hipStream_t stream) {
    const float* uh = (const float*)d_in[0];   // attn_map_uh [8,9,128,64,64] f32
    const float* vw = (const float*)d_in[1];   // attn_map_vw [8,9,128,64,64] f32
    float* out = (float*)d_out;                // [8,2,9,21,64,64] f32

    dim3 grid(H_, A_, B_);   // (h, a, b) = 4608 blocks
    dim3 block(256);
    cost_volume_kernel<<<grid, block, 0, stream>>>(uh, vw, out);
}

// Round 2
// 53.311 us; speedup vs baseline: 1.5302x; 1.5302x over previous
//
#include <hip/hip_runtime.h>

#define DISP_RANGE 10
#define OUT_D 21
#define B_ 8
#define A_ 9
#define D_ 128
#define HW_ 4096   // 64*64

// cost[b,0,a,k,h,w] = wt_k * sum_{dd in [START0+s_k, START0+e_k)} uh[b,a, dd-32+h, h, w]  (0 if row OOB)
// cost[b,1,a,k,h,w] = wt_k * sum_{dd in [START0+s_k, START0+e_k)} vw[b,a, dd-32+w, h, w]  (0 if row OOB)
// Templated on AD = max(|a-4|,1) so L/START0/windows/weights are all constexpr:
// loops fully unroll, loads stream with high MLP. vw rows staged to LDS via
// async global_load_lds (width 16); diagonal LDS read is stride-65 words ->
// bank-conflict-free.

template<int AD, int WID>
__device__ __forceinline__ void compute_group(
    const float* __restrict__ uh_slice,   // uh + plane + h*64
    const float* lds,                     // staged vw rows [LO,HI)
    float* __restrict__ out0,             // out + base(n=0) + w
    float* __restrict__ out1,             // out + base(n=1) + w
    int h, int w)
{
    constexpr int L      = 2 * DISP_RANGE * AD + 1;
    constexpr int START0 = (D_ / 2) - DISP_RANGE * AD;
    constexpr int LO     = (START0 - 32 < 0) ? 0 : (START0 - 32);
    constexpr int HI     = (START0 + L + 31 > D_) ? D_ : (START0 + L + 31);
    constexpr int K0     = (WID == 0) ? 0 : (6 + 5 * (WID - 1));   // 0,6,11,16
    constexpr int K1     = K0 + ((WID == 0) ? 6 : 5);
    constexpr int NK     = K1 - K0;
    constexpr int S0     = (K0 * L) / OUT_D;
    constexpr int E1     = (K1 * L + OUT_D - 1) / OUT_D;           // e_{K1-1}

    float acc0[NK];
    float acc1[NK];
#pragma unroll
    for (int i = 0; i < NK; ++i) { acc0[i] = 0.0f; acc1[i] = 0.0f; }

#pragma unroll
    for (int dd = START0 + S0; dd < START0 + E1; ++dd) {
        // uh path: clamp row, unconditional (in-bounds) load, select
        const int  row  = dd - 32 + h;
        const bool ok0  = (row >= 0) && (row < D_);
        const int  rowc = row < 0 ? 0 : (row > D_ - 1 ? D_ - 1 : row);
        float v0 = uh_slice[(size_t)rowc * HW_ + (size_t)w];
        v0 = ok0 ? v0 : 0.0f;

        // vw path from LDS: per-lane diagonal row, clamp + select
        const int  rv   = dd - 32 + w;
        const bool ok1  = (rv >= LO) && (rv < HI);
        const int  rvc  = rv < LO ? LO : (rv > HI - 1 ? HI - 1 : rv);
        float v1 = lds[(rvc - LO) * 64 + w];
        v1 = ok1 ? v1 : 0.0f;

        // compile-time window membership -> pure adds
#pragma unroll
        for (int k = K0; k < K1; ++k) {
            if (dd >= START0 + (k * L) / OUT_D &&
                dd <  START0 + ((k + 1) * L + OUT_D - 1) / OUT_D) {
                acc0[k - K0] += v0;
                acc1[k - K0] += v1;
            }
        }
    }

#pragma unroll
    for (int k = K0; k < K1; ++k) {
        const int   s  = (k * L) / OUT_D;
        const int   e  = ((k + 1) * L + OUT_D - 1) / OUT_D;
        const float wt = 1.0f / (float)(e - s);
        out0[(size_t)k * HW_] = acc0[k - K0] * wt;
        out1[(size_t)k * HW_] = acc1[k - K0] * wt;
    }
}

template<int AD>
__global__ __launch_bounds__(256) void cost_volume_ad(
    const float* __restrict__ uh,
    const float* __restrict__ vw,
    float* __restrict__ out,
    int a_first, int a_step)
{
    constexpr int L      = 2 * DISP_RANGE * AD + 1;
    constexpr int START0 = (D_ / 2) - DISP_RANGE * AD;
    constexpr int LO     = (START0 - 32 < 0) ? 0 : (START0 - 32);
    constexpr int HI     = (START0 + L + 31 > D_) ? D_ : (START0 + L + 31);
    constexpr int NROWS  = HI - LO;        // 84 / 104 / 124 / 128 (all %4==0)
    constexpr int NCH    = NROWS / 4;      // 4-row chunks, one per wave issue

    __shared__ float lds[NROWS * 64];

    const int h    = blockIdx.x;
    const int a    = a_first + a_step * (int)blockIdx.y;
    const int b    = blockIdx.z;
    const int t    = (int)threadIdx.x;
    const int lane = t & 63;
    const int w    = lane;
    const int wid  = t >> 6;

    const size_t plane = (size_t)(b * A_ + a) * D_ * HW_;
    const float* uh_slice = uh + plane + (size_t)h * 64;
    const float* vw_slice = vw + plane + (size_t)h * 64;

    // ---- async stage vw rows [LO,HI) into LDS ----
    // chunk c = rows [LO+4c, LO+4c+4); wave (c&3) issues it; lane l covers
    // row +(l>>4), float4 col (l&15). LDS dest = base c*1024B + l*16B (linear).
#pragma unroll
    for (int c = 0; c < NCH; ++c) {
        if ((c & 3) == wid) {
            const float* src = vw_slice
                + (size_t)(LO + c * 4 + (lane >> 4)) * HW_
                + (size_t)((lane & 15) * 4);
            __builtin_amdgcn_global_load_lds(
                (const __attribute__((address_space(1))) void*)src,
                (__attribute__((address_space(3))) void*)&lds[c * 256],
                16, 0, 0);
        }
    }
    __syncthreads();

    const size_t out_b0 = ((size_t)(b * 2) * A_ + a) * OUT_D * HW_
                        + (size_t)h * 64 + (size_t)w;
    const size_t out_b1 = out_b0 + (size_t)A_ * OUT_D * HW_;
    float* out0 = out + out_b0;
    float* out1 = out + out_b1;

    switch (wid) {
        case 0: compute_group<AD, 0>(uh_slice, lds, out0, out1, h, w); break;
        case 1: compute_group<AD, 1>(uh_slice, lds, out0, out1, h, w); break;
        case 2: compute_group<AD, 2>(uh_slice, lds, out0, out1, h, w); break;
        default: compute_group<AD, 3>(uh_slice, lds, out0, out1, h, w); break;
    }
}

extern "C" void kernel_launch(void* const* d_in, const int* in_sizes, int n_in,
                              void* d_out, int out_size, void* d_ws, size_t ws_size,
                              hipStream_t stream) {
    const float* uh = (const float*)d_in[0];   // [8,9,128,64,64] f32
    const float* vw = (const float*)d_in[1];   // [8,9,128,64,64] f32
    float* out = (float*)d_out;                // [8,2,9,21,64,64] f32

    dim3 block(256);
    // AD=1: a in {3,4,5}; AD=2: {2,6}; AD=3: {1,7}; AD=4: {0,8}
    cost_volume_ad<1><<<dim3(64, 3, B_), block, 0, stream>>>(uh, vw, out, 3, 1);
    cost_volume_ad<2><<<dim3(64, 2, B_), block, 0, stream>>>(uh, vw, out, 2, 4);
    cost_volume_ad<3><<<dim3(64, 2, B_), block, 0, stream>>>(uh, vw, out, 1, 6);
    cost_volume_ad<4><<<dim3(64, 2, B_), block, 0, stream>>>(uh, vw, out, 0, 8);
}

// Round 3
// 42.007 us; speedup vs baseline: 1.9419x; 1.2691x over previous
//
#include <hip/hip_runtime.h>

#define DISP_RANGE 10
#define OUT_D 21
#define B_ 8
#define A_ 9
#define D_ 128
#define HW_ 4096   // 64*64

// cost[b,0,a,k,h,w] = wt_k * sum_{dd in [START0+s_k, START0+e_k)} uh[b,a, dd-32+h, h, w]  (0 if row OOB)
// cost[b,1,a,k,h,w] = wt_k * sum_{dd in [START0+s_k, START0+e_k)} vw[b,a, dd-32+w, h, w]  (0 if row OOB)
// Single launch; block-uniform switch on a -> AD template so L/START0/windows/
// weights are constexpr (full unroll, streaming loads). vw rows staged to LDS
// via async global_load_lds (width 16); diagonal LDS read stride-65 words ->
// bank-conflict-free.

template<int AD, int WID>
__device__ __forceinline__ void compute_group(
    const float* __restrict__ uh_slice,   // uh + plane + h*64
    const float* lds,                     // staged vw rows [LO,HI)
    float* __restrict__ out0,             // out + base(n=0) + w
    float* __restrict__ out1,             // out + base(n=1) + w
    int h, int w)
{
    constexpr int L      = 2 * DISP_RANGE * AD + 1;
    constexpr int START0 = (D_ / 2) - DISP_RANGE * AD;
    constexpr int LO     = (START0 - 32 < 0) ? 0 : (START0 - 32);
    constexpr int HI     = (START0 + L + 31 > D_) ? D_ : (START0 + L + 31);
    constexpr int K0     = (WID == 0) ? 0 : (6 + 5 * (WID - 1));   // 0,6,11,16
    constexpr int K1     = K0 + ((WID == 0) ? 6 : 5);
    constexpr int NK     = K1 - K0;
    constexpr int S0     = (K0 * L) / OUT_D;
    constexpr int E1     = (K1 * L + OUT_D - 1) / OUT_D;           // e_{K1-1}

    float acc0[NK];
    float acc1[NK];
#pragma unroll
    for (int i = 0; i < NK; ++i) { acc0[i] = 0.0f; acc1[i] = 0.0f; }

#pragma unroll
    for (int dd = START0 + S0; dd < START0 + E1; ++dd) {
        // uh path: clamp row, unconditional (in-bounds) load, select
        const int  row  = dd - 32 + h;
        const bool ok0  = (row >= 0) && (row < D_);
        const int  rowc = row < 0 ? 0 : (row > D_ - 1 ? D_ - 1 : row);
        float v0 = uh_slice[(size_t)rowc * HW_ + (size_t)w];
        v0 = ok0 ? v0 : 0.0f;

        // vw path from LDS: per-lane diagonal row, clamp + select
        const int  rv   = dd - 32 + w;
        const bool ok1  = (rv >= LO) && (rv < HI);
        const int  rvc  = rv < LO ? LO : (rv > HI - 1 ? HI - 1 : rv);
        float v1 = lds[(rvc - LO) * 64 + w];
        v1 = ok1 ? v1 : 0.0f;

        // compile-time window membership -> pure adds
#pragma unroll
        for (int k = K0; k < K1; ++k) {
            if (dd >= START0 + (k * L) / OUT_D &&
                dd <  START0 + ((k + 1) * L + OUT_D - 1) / OUT_D) {
                acc0[k - K0] += v0;
                acc1[k - K0] += v1;
            }
        }
    }

#pragma unroll
    for (int k = K0; k < K1; ++k) {
        const int   s  = (k * L) / OUT_D;
        const int   e  = ((k + 1) * L + OUT_D - 1) / OUT_D;
        const float wt = 1.0f / (float)(e - s);
        out0[(size_t)k * HW_] = acc0[k - K0] * wt;
        out1[(size_t)k * HW_] = acc1[k - K0] * wt;
    }
}

template<int AD>
__device__ __forceinline__ void run_block(
    const float* __restrict__ uh,
    const float* __restrict__ vw,
    float* __restrict__ out,
    float* lds,
    int b, int a, int h, int t)
{
    constexpr int L      = 2 * DISP_RANGE * AD + 1;
    constexpr int START0 = (D_ / 2) - DISP_RANGE * AD;
    constexpr int LO     = (START0 - 32 < 0) ? 0 : (START0 - 32);
    constexpr int HI     = (START0 + L + 31 > D_) ? D_ : (START0 + L + 31);
    constexpr int NROWS  = HI - LO;        // 84 / 104 / 124 / 128 (all %4==0)
    constexpr int NCH    = NROWS / 4;      // 4-row chunks, one per wave issue

    const int lane = t & 63;
    const int w    = lane;
    const int wid  = t >> 6;

    const size_t plane = (size_t)(b * A_ + a) * D_ * HW_;
    const float* uh_slice = uh + plane + (size_t)h * 64;
    const float* vw_slice = vw + plane + (size_t)h * 64;

    // ---- async stage vw rows [LO,HI) into LDS ----
    // chunk c = rows [LO+4c, LO+4c+4); wave (c&3) issues it; lane l covers
    // row +(l>>4), float4 col (l&15). LDS dest = base c*1024B + l*16B (linear).
#pragma unroll
    for (int c = 0; c < NCH; ++c) {
        if ((c & 3) == wid) {
            const float* src = vw_slice
                + (size_t)(LO + c * 4 + (lane >> 4)) * HW_
                + (size_t)((lane & 15) * 4);
            __builtin_amdgcn_global_load_lds(
                (const __attribute__((address_space(1))) void*)src,
                (__attribute__((address_space(3))) void*)&lds[c * 256],
                16, 0, 0);
        }
    }
    __syncthreads();

    const size_t out_b0 = ((size_t)(b * 2) * A_ + a) * OUT_D * HW_
                        + (size_t)h * 64 + (size_t)w;
    const size_t out_b1 = out_b0 + (size_t)A_ * OUT_D * HW_;
    float* out0 = out + out_b0;
    float* out1 = out + out_b1;

    switch (wid) {
        case 0: compute_group<AD, 0>(uh_slice, lds, out0, out1, h, w); break;
        case 1: compute_group<AD, 1>(uh_slice, lds, out0, out1, h, w); break;
        case 2: compute_group<AD, 2>(uh_slice, lds, out0, out1, h, w); break;
        default: compute_group<AD, 3>(uh_slice, lds, out0, out1, h, w); break;
    }
}

__global__ __launch_bounds__(256) void cost_volume_kernel(
    const float* __restrict__ uh,
    const float* __restrict__ vw,
    float* __restrict__ out)
{
    __shared__ float lds[D_ * 64];   // 32 KiB (max case AD=4)

    const int h = blockIdx.x;
    const int a = blockIdx.y;
    const int b = blockIdx.z;
    const int t = (int)threadIdx.x;

    // AD = max(|a-4|,1), block-uniform branch into constexpr path
    switch (a) {
        case 3: case 4: case 5:
            run_block<1>(uh, vw, out, lds, b, a, h, t); break;
        case 2: case 6:
            run_block<2>(uh, vw, out, lds, b, a, h, t); break;
        case 1: case 7:
            run_block<3>(uh, vw, out, lds, b, a, h, t); break;
        default:   // 0, 8
            run_block<4>(uh, vw, out, lds, b, a, h, t); break;
    }
}

extern "C" void kernel_launch(void* const* d_in, const int* in_sizes, int n_in,
                              void* d_out, int out_size, void* d_ws, size_t ws_size,
                              hipStream_t stream) {
    const float* uh = (const float*)d_in[0];   // [8,9,128,64,64] f32
    const float* vw = (const float*)d_in[1];   // [8,9,128,64,64] f32
    float* out = (float*)d_out;                // [8,2,9,21,64,64] f32

    dim3 grid(64, A_, B_);   // (h, a, b) = 4608 blocks
    dim3 block(256);
    cost_volume_kernel<<<grid, block, 0, stream>>>(uh, vw, out);
}